// Round 1
// baseline (2523.399 us; speedup 1.0000x reference)
//
#include <hip/hip_runtime.h>

#define B 8
#define N 8192
#define S 2048
#define K 32
#define TPB 512           // all blocks: 8 waves
#define PPT (N / TPB)     // 16 contiguous points per FPS thread
#define CHUNK_STEP 128    // FPS publish cadence
#define WPB 31            // worker blocks per batch
#define WVB (WPB * 8)     // 248 KNN waves per batch (stride)

// Exact (no-FMA, left-to-right) squared distance to match numpy fp32:
// ((dx*dx + dy*dy) + dz*dz). FPS argmax is a chaotic recurrence; any ulp
// difference diverges the center sequence. Verified absmax==0 (R1-R8).
__device__ __forceinline__ float sqdist3(float ax, float ay, float az,
                                         float bx, float by, float bz) {
    float dx = ax - bx, dy = ay - by, dz = az - bz;
    return __fadd_rn(__fadd_rn(__fmul_rn(dx, dx), __fmul_rn(dy, dy)),
                     __fmul_rn(dz, dz));
}

template <int CTRL>
__device__ __forceinline__ float dpp_fmax(float v) {
    const int iv = __float_as_int(v);
    const int sh = __builtin_amdgcn_update_dpp(iv, iv, CTRL, 0xF, 0xF, false);
    return fmaxf(v, __int_as_float(sh));
}
__device__ __forceinline__ float wave_fmax_dpp(float v) {
    v = dpp_fmax<0x111>(v);  // row_shr:1
    v = dpp_fmax<0x112>(v);  // row_shr:2
    v = dpp_fmax<0x114>(v);  // row_shr:4
    v = dpp_fmax<0x118>(v);  // row_shr:8
    v = dpp_fmax<0x142>(v);  // row_bcast:15
    v = dpp_fmax<0x143>(v);  // row_bcast:31 -> lane 63 = wave max
    return __int_as_float(__builtin_amdgcn_readlane(__float_as_int(v), 63));
}

// ---------------------------------------------------------------------------
// R9 change: de-scratch the FPS hot loop.
//  - Previous version published winner COORDINATES, gathered via x[bi] with
//    runtime bi -> dynamically-indexed register arrays -> compiler demoted
//    x/y/z to scratch/AGPR (VGPR_Count=68 < the 80+ floats needed). Every
//    step re-streamed ~96 KB/CU of point data -> ~2x step-time inflation.
//  - Now: owner publishes (wmax, global point id). bi comes from the
//    statically-indexed md[] compare chain and feeds only integer math, so
//    x/y/z/md stay in ArchVGPRs. Winner coords are resolved post-scan by a
//    broadcast LDS read from a 96 KB LDS mirror of this batch's xyz
//    (96 KB mirror + 24 KB cent < 160 KB LDS; also forces 1 block/CU so no
//    worker ever co-resides with an FPS block).
//  - Arithmetic is bit-identical: same sqdist3, same fmin order, same
//    lowest-index tie-breaks (thread: descending overwrite; wave: ballot
//    ctz; block: strict-> scan from w=0). Coords are exact copies of xb.
// Tie-break invariants unchanged: FPS (max dist, min gid); KNN (d, idx)
// lexicographic == stable top_k. absmax must stay 0.
// ---------------------------------------------------------------------------
__global__ __launch_bounds__(TPB, 2) void fused_kernel(
    const float* __restrict__ xyz, float* __restrict__ out,
    float* __restrict__ centers, unsigned* __restrict__ progress) {
    const int blk = blockIdx.x;
    const int t = threadIdx.x;
    const int lane = t & 63;

    __shared__ float xyzs[3 * N];      // 96 KB point mirror (FPS blocks only)
    __shared__ float cent[S * 3];      // centers staged in LDS (24 KB)
    __shared__ float2 pub[2][8];       // per-wave {wmax, gid}, dbuf

    if (blk < B) {
        // =================== FPS producer ===================
        const int b = blk;
        const float* xb = xyz + (size_t)b * N * 3;
        float* cb = centers + (size_t)b * S * 3;
        const int wid = t >> 6;

        float x[PPT], y[PPT], z[PPT], md[PPT];
        {
            float raw[3 * PPT];
            const float4* src = (const float4*)(xb + 3 * PPT * t);
            float4* dst = (float4*)(xyzs + 3 * PPT * t);
#pragma unroll
            for (int i = 0; i < 3 * PPT / 4; ++i) {
                const float4 v = src[i];
                dst[i] = v;                     // one-time LDS mirror
                raw[4 * i + 0] = v.x; raw[4 * i + 1] = v.y;
                raw[4 * i + 2] = v.z; raw[4 * i + 3] = v.w;
            }
#pragma unroll
            for (int i = 0; i < PPT; ++i) {
                x[i] = raw[3 * i + 0];
                y[i] = raw[3 * i + 1];
                z[i] = raw[3 * i + 2];
                md[i] = INFINITY;
            }
        }

        float px = xb[0], py = xb[1], pz = xb[2];   // step 0: point 0
        if (t == 0) { cent[0] = px; cent[1] = py; cent[2] = pz; }

        for (int s = 1; s < S; ++s) {
            // local update; tree max (values only, all static indices)
            float m[PPT];
#pragma unroll
            for (int i = 0; i < PPT; ++i) {
                const float d = sqdist3(x[i], y[i], z[i], px, py, pz);
                m[i] = fminf(md[i], d);
                md[i] = m[i];
            }
#pragma unroll
            for (int st = 1; st < PPT; st <<= 1)
#pragma unroll
                for (int i = 0; i < PPT; i += 2 * st)
                    m[i] = fmaxf(m[i], m[i + st]);
            const float best = m[0];

            // wave max (DPP) + first-lane tie-break via ballot
            const float wmax = wave_fmax_dpp(best);
            const unsigned long long mb = __ballot(best == wmax);
            const int ol = (int)__builtin_ctzll(mb);

            // owner: re-derive lowest i (descending overwrite, static
            // indices on md only), publish {wmax, global id} -- 8 bytes,
            // no runtime-indexed register access anywhere.
            const int pb = s & 1;
            if (lane == ol) {
                int bi = 0;
#pragma unroll
                for (int i = PPT - 1; i >= 0; --i)
                    if (md[i] == wmax) bi = i;
                const int gid = PPT * t + bi;
                pub[pb][wid] = make_float2(wmax, __int_as_float(gid));
            }
            __syncthreads();               // the ONLY per-step barrier

            // serial scan of 8 wave winners (strict > -> lowest wid on ties)
            float2 v0 = pub[pb][0];
            float gmax = v0.x;
            int gbest = __float_as_int(v0.y);
#pragma unroll
            for (int w = 1; w < 8; ++w) {
                const float2 u = pub[pb][w];
                const bool g = u.x > gmax;
                gmax = g ? u.x : gmax;
                gbest = g ? __float_as_int(u.y) : gbest;
            }
            // resolve winner coords: broadcast LDS read (bit-exact copy)
            px = xyzs[3 * gbest + 0];
            py = xyzs[3 * gbest + 1];
            pz = xyzs[3 * gbest + 2];
            if (t == 0) {
                cent[3 * s + 0] = px;
                cent[3 * s + 1] = py;
                cent[3 * s + 2] = pz;
            }

            // ---- chunk publish: barrier, copy, barrier (vmcnt drain), release
            if ((s & (CHUNK_STEP - 1)) == (CHUNK_STEP - 1)) {
                __syncthreads();           // t0's cent[3s] visible to copiers
                const int base = 3 * (s - (CHUNK_STEP - 1));
                if (t < 3 * CHUNK_STEP) cb[base + t] = cent[base + t];
                __syncthreads();           // drains copiers' stores (vmcnt0)
                if (t == 0)
                    __hip_atomic_store(&progress[b], (unsigned)(s + 1),
                                       __ATOMIC_RELEASE, __HIP_MEMORY_SCOPE_AGENT);
            }
        }
    } else {
        // ======================= KNN workers ===============================
        const int w = blk - B;
        const int b = w & 7;               // same XCD as FPS block b (%8 rr)
        const int wchunk = w >> 3;         // 0..30
        const int waveid = wchunk * 8 + (t >> 6);   // 0..247 within batch
        const float* xb = xyz + (size_t)b * N * 3;

        unsigned seen = 0;                 // register-cached progress[b]
        for (int s = waveid; s < S; s += WVB) {
            // wait until progress[b] > s (all lanes load same line ->
            // broadcast; ACQUIRE invalidates L1 so center reads are fresh)
            while (seen <= (unsigned)s) {
                seen = __hip_atomic_load(&progress[b], __ATOMIC_ACQUIRE,
                                         __HIP_MEMORY_SCOPE_AGENT);
                if (seen <= (unsigned)s) __builtin_amdgcn_s_sleep(64);
            }

            const float* c = centers + (size_t)(b * S + s) * 3;
            const float cx = c[0], cy = c[1], cz = c[2];

            unsigned long long P = ~0ULL;   // lanes 0..31: sorted top-32 (asc)
            unsigned long long tau = ~0ULL;

            for (int i = 0; i < N / 64; ++i) {
                const int p = (i << 6) + lane;
                const float* q = xb + 3 * p;
                const float d = sqdist3(q[0], q[1], q[2], cx, cy, cz);
                const unsigned long long cand =
                    ((unsigned long long)__float_as_uint(d) << 32) | (unsigned)p;
                bool alive = cand < tau;
                unsigned long long mask = __ballot(alive);
                while (mask) {
                    const int src = __builtin_ctzll(mask);
                    const unsigned long long bc = __shfl(cand, src);
                    unsigned long long up = __shfl_up(P, 1);
                    if (lane == 0) up = bc;
                    const bool gt = P > bc;
                    const unsigned long long shifted = (up > bc) ? up : bc;
                    P = gt ? shifted : P;
                    tau = __shfl(P, 31);
                    if (lane == src) alive = false;
                    alive = alive && (cand < tau);
                    mask = __ballot(alive);
                }
            }

            if (lane < K) {
                const unsigned nidx = (unsigned)P;
                const float* q = xb + 3 * nidx;
                float* o = out + ((size_t)(b * S + s) * K + lane) * 3;
                o[0] = q[0] - cx;
                o[1] = q[1] - cy;
                o[2] = q[2] - cz;
            }
        }
    }
}

extern "C" void kernel_launch(void* const* d_in, const int* in_sizes, int n_in,
                              void* d_out, int out_size, void* d_ws, size_t ws_size,
                              hipStream_t stream) {
    const float* xyz = (const float*)d_in[0];
    float* out = (float*)d_out;                         // neighborhood [B,S,K,3]
    float* centers = out + (size_t)B * S * K * 3;       // centers [B,S,3]
    unsigned* progress = (unsigned*)d_ws;               // [B] centers-ready count

    // d_ws is poisoned 0xAA before every timed launch -> must zero progress
    hipMemsetAsync(d_ws, 0, B * sizeof(unsigned), stream);

    fused_kernel<<<B + WPB * B, TPB, 0, stream>>>(xyz, out, centers, progress);
}

// Round 2
// 2164.884 us; speedup vs baseline: 1.1656x; 1.1656x over previous
//
#include <hip/hip_runtime.h>

#define B 8
#define N 8192
#define S 2048
#define K 32
#define TPB 512           // all blocks: 8 waves
#define PPT (N / TPB)     // 16 contiguous points per FPS thread
#define CHUNK_STEP 128    // FPS publish cadence
#define WPB 31            // worker blocks per batch
#define WVB (WPB * 8)     // 248 KNN waves per batch (stride)

// Exact (no-FMA, left-to-right) squared distance to match numpy fp32:
// ((dx*dx + dy*dy) + dz*dz). FPS argmax is a chaotic recurrence; any ulp
// difference diverges the center sequence. Verified absmax==0 (R1-R9).
__device__ __forceinline__ float sqdist3(float ax, float ay, float az,
                                         float bx, float by, float bz) {
    float dx = ax - bx, dy = ay - by, dz = az - bz;
    return __fadd_rn(__fadd_rn(__fmul_rn(dx, dx), __fmul_rn(dy, dy)),
                     __fmul_rn(dz, dz));
}

template <int CTRL>
__device__ __forceinline__ float dpp_fmax(float v) {
    const int iv = __float_as_int(v);
    const int sh = __builtin_amdgcn_update_dpp(iv, iv, CTRL, 0xF, 0xF, false);
    return fmaxf(v, __int_as_float(sh));
}
__device__ __forceinline__ float wave_fmax_dpp(float v) {
    v = dpp_fmax<0x111>(v);  // row_shr:1
    v = dpp_fmax<0x112>(v);  // row_shr:2
    v = dpp_fmax<0x114>(v);  // row_shr:4
    v = dpp_fmax<0x118>(v);  // row_shr:8
    v = dpp_fmax<0x142>(v);  // row_bcast:15
    v = dpp_fmax<0x143>(v);  // row_bcast:31 -> lane 63 = wave max
    return __int_as_float(__builtin_amdgcn_readlane(__float_as_int(v), 63));
}

// ---------------------------------------------------------------------------
// R10: keep R9's static-index-only register discipline, drop R9's regression.
//  - R9 post-mortem: adding a serial LDS coord read AFTER the winner scan
//    cost ~+0.09 us/step (2343->2523). The de-scratch gain was ~0, so the
//    per-step cost is latency-CHAIN-bound: never add to the post-barrier
//    serial path.
//  - Owner lane now selects winning coords via statically-indexed descending
//    overwrite (if (md[i]==wmax){bx=x[i];..} for i=PPT-1..0 -> lowest i wins,
//    pure cndmask chain, no dynamic register indexing, no scratch) and
//    publishes float4(wmax,bx,by,bz). Coords ride inline in the pub scan --
//    R0's dataflow with R9's register hygiene. No 96 KB mirror, no extra read.
//  - cent LDS staging + 2 chunk barriers removed: t0 stores each center
//    directly to global as it is found; only t0 writes centers, and the
//    agent-RELEASE store of progress[b] drains t0's vmcnt first, so workers
//    acquiring progress>s see all centers <= s. (Release/acquire at agent
//    scope handles cross-XCD L2 visibility -- same mechanism as R0-R9,
//    absmax==0 across all dispatches.)
// Tie-break invariants unchanged: FPS (max dist, min gid): thread = lowest i
// (descending overwrite), wave = lowest lane (ballot ctz), block = lowest wid
// (strict > scan from w=0); KNN (d, idx) lexicographic == stable top_k.
// absmax must stay 0.
// ---------------------------------------------------------------------------
__global__ __launch_bounds__(TPB, 2) void fused_kernel(
    const float* __restrict__ xyz, float* __restrict__ out,
    float* __restrict__ centers, unsigned* __restrict__ progress) {
    const int blk = blockIdx.x;
    const int t = threadIdx.x;
    const int lane = t & 63;

    __shared__ float4 pub[2][8];       // per-wave {wmax,x,y,z}, dbuf

    if (blk < B) {
        // =================== FPS producer ===================
        const int b = blk;
        const float* xb = xyz + (size_t)b * N * 3;
        float* cb = centers + (size_t)b * S * 3;
        const int wid = t >> 6;

        float x[PPT], y[PPT], z[PPT], md[PPT];
        {
            float raw[3 * PPT];
            const float4* src = (const float4*)(xb + 3 * PPT * t);
#pragma unroll
            for (int i = 0; i < 3 * PPT / 4; ++i) {
                const float4 v = src[i];
                raw[4 * i + 0] = v.x; raw[4 * i + 1] = v.y;
                raw[4 * i + 2] = v.z; raw[4 * i + 3] = v.w;
            }
#pragma unroll
            for (int i = 0; i < PPT; ++i) {
                x[i] = raw[3 * i + 0];
                y[i] = raw[3 * i + 1];
                z[i] = raw[3 * i + 2];
                md[i] = INFINITY;
            }
        }

        float px = xb[0], py = xb[1], pz = xb[2];   // step 0: point 0
        if (t == 0) { cb[0] = px; cb[1] = py; cb[2] = pz; }

        for (int s = 1; s < S; ++s) {
            // local update; tree max (values only, all static indices)
            float m[PPT];
#pragma unroll
            for (int i = 0; i < PPT; ++i) {
                const float d = sqdist3(x[i], y[i], z[i], px, py, pz);
                m[i] = fminf(md[i], d);
                md[i] = m[i];
            }
#pragma unroll
            for (int st = 1; st < PPT; st <<= 1)
#pragma unroll
                for (int i = 0; i < PPT; i += 2 * st)
                    m[i] = fmaxf(m[i], m[i + st]);
            const float best = m[0];

            // wave max (DPP) + first-lane tie-break via ballot
            const float wmax = wave_fmax_dpp(best);
            const unsigned long long mb = __ballot(best == wmax);
            const int ol = (int)__builtin_ctzll(mb);

            // owner: statically-indexed descending overwrite selects the
            // lowest-i match's coords (pure cndmask chain, no dynamic
            // register indexing anywhere) and publishes them inline.
            const int pb = s & 1;
            if (lane == ol) {
                float bx = x[0], by = y[0], bz = z[0];
#pragma unroll
                for (int i = PPT - 1; i >= 0; --i)
                    if (md[i] == wmax) { bx = x[i]; by = y[i]; bz = z[i]; }
                pub[pb][wid] = make_float4(wmax, bx, by, bz);
            }
            __syncthreads();               // the ONLY per-step barrier

            // serial scan of 8 wave winners (strict > -> lowest wid on ties)
            float4 v0 = pub[pb][0];
            float gmax = v0.x;
            px = v0.y; py = v0.z; pz = v0.w;
#pragma unroll
            for (int w = 1; w < 8; ++w) {
                const float4 u = pub[pb][w];
                const bool g = u.x > gmax;
                gmax = g ? u.x : gmax;
                px = g ? u.y : px;
                py = g ? u.z : py;
                pz = g ? u.w : pz;
            }

            // t0 streams the center straight to global (only t0 ever writes
            // centers; fire-and-forget, drained by the release below)
            if (t == 0) {
                float* cs = cb + 3 * s;
                cs[0] = px; cs[1] = py; cs[2] = pz;
            }

            // chunk publish: release store orders t0's prior center stores
            // (compiler emits vmcnt(0) drain + agent-scope writeback)
            if ((s & (CHUNK_STEP - 1)) == (CHUNK_STEP - 1)) {
                if (t == 0)
                    __hip_atomic_store(&progress[b], (unsigned)(s + 1),
                                       __ATOMIC_RELEASE, __HIP_MEMORY_SCOPE_AGENT);
            }
        }
    } else {
        // ======================= KNN workers ===============================
        const int w = blk - B;
        const int b = w & 7;               // same XCD as FPS block b (%8 rr)
        const int wchunk = w >> 3;         // 0..30
        const int waveid = wchunk * 8 + (t >> 6);   // 0..247 within batch
        const float* xb = xyz + (size_t)b * N * 3;

        unsigned seen = 0;                 // register-cached progress[b]
        for (int s = waveid; s < S; s += WVB) {
            // wait until progress[b] > s (all lanes load same line ->
            // broadcast; ACQUIRE invalidates L1 so center reads are fresh)
            while (seen <= (unsigned)s) {
                seen = __hip_atomic_load(&progress[b], __ATOMIC_ACQUIRE,
                                         __HIP_MEMORY_SCOPE_AGENT);
                if (seen <= (unsigned)s) __builtin_amdgcn_s_sleep(64);
            }

            const float* c = centers + (size_t)(b * S + s) * 3;
            const float cx = c[0], cy = c[1], cz = c[2];

            unsigned long long P = ~0ULL;   // lanes 0..31: sorted top-32 (asc)
            unsigned long long tau = ~0ULL;

            for (int i = 0; i < N / 64; ++i) {
                const int p = (i << 6) + lane;
                const float* q = xb + 3 * p;
                const float d = sqdist3(q[0], q[1], q[2], cx, cy, cz);
                const unsigned long long cand =
                    ((unsigned long long)__float_as_uint(d) << 32) | (unsigned)p;
                bool alive = cand < tau;
                unsigned long long mask = __ballot(alive);
                while (mask) {
                    const int src = __builtin_ctzll(mask);
                    const unsigned long long bc = __shfl(cand, src);
                    unsigned long long up = __shfl_up(P, 1);
                    if (lane == 0) up = bc;
                    const bool gt = P > bc;
                    const unsigned long long shifted = (up > bc) ? up : bc;
                    P = gt ? shifted : P;
                    tau = __shfl(P, 31);
                    if (lane == src) alive = false;
                    alive = alive && (cand < tau);
                    mask = __ballot(alive);
                }
            }

            if (lane < K) {
                const unsigned nidx = (unsigned)P;
                const float* q = xb + 3 * nidx;
                float* o = out + ((size_t)(b * S + s) * K + lane) * 3;
                o[0] = q[0] - cx;
                o[1] = q[1] - cy;
                o[2] = q[2] - cz;
            }
        }
    }
}

extern "C" void kernel_launch(void* const* d_in, const int* in_sizes, int n_in,
                              void* d_out, int out_size, void* d_ws, size_t ws_size,
                              hipStream_t stream) {
    const float* xyz = (const float*)d_in[0];
    float* out = (float*)d_out;                         // neighborhood [B,S,K,3]
    float* centers = out + (size_t)B * S * K * 3;       // centers [B,S,3]
    unsigned* progress = (unsigned*)d_ws;               // [B] centers-ready count

    // d_ws is poisoned 0xAA before every timed launch -> must zero progress
    hipMemsetAsync(d_ws, 0, B * sizeof(unsigned), stream);

    fused_kernel<<<B + WPB * B, TPB, 0, stream>>>(xyz, out, centers, progress);
}